// Round 3
// baseline (700.805 us; speedup 1.0000x reference)
//
#include <hip/hip_runtime.h>
#include <stdint.h>

// Attention block: out = (softmax((x Wq^T + bq)(x Wk^T + bk)^T / sqrt(128)) (x Wv^T + bv)) Wo^T + bo + x
// N=8192 tokens, D=1024. All GEMMs in bf16 MFMA (fp32 accum), m97-style 128x128 tile.

#define NTOK 8192
#define DMOD 1024
static constexpr float INV_SCALE = 0.08838834764831845f; // 1/sqrt(128)

typedef __attribute__((ext_vector_type(8))) short short8;   // 8 bf16 (guide §3 frag_ab)
typedef __attribute__((ext_vector_type(4))) float f32x4;
typedef __attribute__((ext_vector_type(8))) unsigned short u16x8;
typedef __attribute__((ext_vector_type(4))) unsigned short u16x4;

__device__ __forceinline__ unsigned short f2bf(float f) {
  union { float f; uint32_t u; } x{f};
  uint32_t r = x.u + 0x7fffu + ((x.u >> 16) & 1u);
  return (unsigned short)(r >> 16);
}
__device__ __forceinline__ float bf2f(unsigned short b) {
  return __uint_as_float(((uint32_t)b) << 16);
}
__device__ __forceinline__ void async16(void* lds, const void* g) {
  __builtin_amdgcn_global_load_lds((const __attribute__((address_space(1))) void*)g,
                                   (__attribute__((address_space(3))) void*)lds, 16, 0, 0);
}

// ---------------- cast f32 -> bf16 ----------------
__global__ __launch_bounds__(256) void cast_f32_bf16(const float* __restrict__ in,
                                                     unsigned short* __restrict__ out, int n4) {
  int i = blockIdx.x * 256 + threadIdx.x;
  int stride = gridDim.x * 256;
  for (; i < n4; i += stride) {
    float4 v = ((const float4*)in)[i];
    u16x4 o;
    o[0] = f2bf(v.x); o[1] = f2bf(v.y); o[2] = f2bf(v.z); o[3] = f2bf(v.w);
    ((u16x4*)out)[i] = o;
  }
}

// ---------------- GEMM: C = A (MxK) * B^T (B is NxK), bf16 in, epilogue variants ----------------
// 256 threads = 4 waves (2x2), each wave 64x64 = 4x4 frags of 16x16, BK=32.
template<bool BIAS, bool TRANS, bool F32OUT, bool RES>
__global__ __launch_bounds__(256) void gemm_bt(
    const unsigned short* __restrict__ A, const unsigned short* __restrict__ B,
    unsigned short* __restrict__ O16, float* __restrict__ O32,
    const float* __restrict__ bias, const float* __restrict__ resid,
    int M, int N, int K, float scale)
{
  __shared__ unsigned short As[128 * 32];
  __shared__ unsigned short Bs[128 * 32];
  const int t = threadIdx.x;
  const int row0 = blockIdx.y * 128;
  const int col0 = blockIdx.x * 128;
  const int w = t >> 6, l = t & 63;
  const int wr = (w >> 1) * 64, wc = (w & 1) * 64;
  const int lr = l & 15;
  const int lk = (l >> 4) * 8;

  const int srow = t >> 2;          // staging row 0..63
  const int scol = (t & 3) * 8;     // staging k-offset (8 bf16 = 16B)

  const unsigned short* gA0 = A + (size_t)(row0 + srow) * K + scol;
  const unsigned short* gA1 = A + (size_t)(row0 + 64 + srow) * K + scol;
  const unsigned short* gB0 = B + (size_t)(col0 + srow) * K + scol;
  const unsigned short* gB1 = B + (size_t)(col0 + 64 + srow) * K + scol;
  unsigned short* lA0 = As + t * 8;
  unsigned short* lA1 = As + 2048 + t * 8;
  unsigned short* lB0 = Bs + t * 8;
  unsigned short* lB1 = Bs + 2048 + t * 8;

  f32x4 acc[4][4] = {};

  for (int k0 = 0; k0 < K; k0 += 32) {
    __syncthreads();                 // prev tile fully consumed
    async16(lA0, gA0 + k0);
    async16(lA1, gA1 + k0);
    async16(lB0, gB0 + k0);
    async16(lB1, gB1 + k0);
    __syncthreads();                 // drains vmcnt(0) -> tile visible
    short8 a[4], b[4];
#pragma unroll
    for (int m = 0; m < 4; ++m)
      a[m] = *(const short8*)(As + (wr + m * 16 + lr) * 32 + lk);
#pragma unroll
    for (int n = 0; n < 4; ++n)
      b[n] = *(const short8*)(Bs + (wc + n * 16 + lr) * 32 + lk);
#pragma unroll
    for (int m = 0; m < 4; ++m)
#pragma unroll
      for (int n = 0; n < 4; ++n)
        acc[m][n] = __builtin_amdgcn_mfma_f32_16x16x32_bf16(a[m], b[n], acc[m][n], 0, 0, 0);
  }

  // C/D layout (m89-verified): col = lane&15, row = (lane>>4)*4 + reg
  const int rr = (l >> 4) * 4;
#pragma unroll
  for (int m = 0; m < 4; ++m) {
#pragma unroll
    for (int n = 0; n < 4; ++n) {
#pragma unroll
      for (int j = 0; j < 4; ++j) {
        int r = row0 + wr + m * 16 + rr + j;
        int c = col0 + wc + n * 16 + lr;
        float v = acc[m][n][j];
        if (BIAS) v += bias[c];
        v *= scale;
        if (RES) v += resid[(size_t)r * N + c];
        if (F32OUT) O32[(size_t)r * N + c] = v;
        else if (TRANS) O16[(size_t)c * M + r] = f2bf(v);
        else O16[(size_t)r * N + c] = f2bf(v);
      }
    }
  }
}

// ---------------- row softmax in-place on bf16 [8192 x 8192] ----------------
__global__ __launch_bounds__(256) void softmax_inplace(unsigned short* __restrict__ S) {
  __shared__ float red[8];
  const int t = threadIdx.x;
  unsigned short* rp = S + (size_t)blockIdx.x * NTOK;
  float v[32];
#pragma unroll
  for (int i = 0; i < 4; ++i) {
    u16x8 u = ((const u16x8*)rp)[t + i * 256];
#pragma unroll
    for (int j = 0; j < 8; ++j) v[i * 8 + j] = bf2f(u[j]);
  }
  float m = -1e30f;
#pragma unroll
  for (int k = 0; k < 32; ++k) m = fmaxf(m, v[k]);
#pragma unroll
  for (int o = 32; o; o >>= 1) m = fmaxf(m, __shfl_xor(m, o));
  if ((t & 63) == 0) red[t >> 6] = m;
  __syncthreads();
  m = fmaxf(fmaxf(red[0], red[1]), fmaxf(red[2], red[3]));
  float s = 0.f;
#pragma unroll
  for (int k = 0; k < 32; ++k) { v[k] = __expf(v[k] - m); s += v[k]; }
#pragma unroll
  for (int o = 32; o; o >>= 1) s += __shfl_xor(s, o);
  if ((t & 63) == 0) red[4 + (t >> 6)] = s;
  __syncthreads();
  s = red[4] + red[5] + red[6] + red[7];
  float inv = 1.0f / s;
#pragma unroll
  for (int i = 0; i < 4; ++i) {
    u16x8 u;
#pragma unroll
    for (int j = 0; j < 8; ++j) u[j] = f2bf(v[i * 8 + j] * inv);
    ((u16x8*)rp)[t + i * 256] = u;
  }
}

extern "C" void kernel_launch(void* const* d_in, const int* in_sizes, int n_in,
                              void* d_out, int out_size, void* d_ws, size_t ws_size,
                              hipStream_t stream) {
  const float* x  = (const float*)d_in[0];
  const float* Wq = (const float*)d_in[1];
  const float* bq = (const float*)d_in[2];
  const float* Wk = (const float*)d_in[3];
  const float* bk = (const float*)d_in[4];
  const float* Wv = (const float*)d_in[5];
  const float* bv = (const float*)d_in[6];
  const float* Wo = (const float*)d_in[7];
  const float* bo = (const float*)d_in[8];
  float* out = (float*)d_out;

  char* p = (char*)d_ws;
  unsigned short* xb  = (unsigned short*)p; p += (size_t)NTOK * DMOD * 2;   // 16 MB
  unsigned short* Wqb = (unsigned short*)p; p += (size_t)DMOD * DMOD * 2;   // 2 MB
  unsigned short* Wkb = (unsigned short*)p; p += (size_t)DMOD * DMOD * 2;
  unsigned short* Wvb = (unsigned short*)p; p += (size_t)DMOD * DMOD * 2;
  unsigned short* Wob = (unsigned short*)p; p += (size_t)DMOD * DMOD * 2;
  unsigned short* Qb  = (unsigned short*)p; p += (size_t)NTOK * DMOD * 2;
  unsigned short* Kb  = (unsigned short*)p; p += (size_t)NTOK * DMOD * 2;
  unsigned short* Vt  = (unsigned short*)p; p += (size_t)DMOD * NTOK * 2;   // V transposed [D][N]
  unsigned short* Ob  = (unsigned short*)p; p += (size_t)NTOK * DMOD * 2;
  unsigned short* S   = (unsigned short*)p; p += (size_t)NTOK * NTOK * 2;   // 128 MB

  // casts
  cast_f32_bf16<<<dim3(2048), dim3(256), 0, stream>>>(x, xb, NTOK * DMOD / 4);
  cast_f32_bf16<<<dim3(1024), dim3(256), 0, stream>>>(Wq, Wqb, DMOD * DMOD / 4);
  cast_f32_bf16<<<dim3(1024), dim3(256), 0, stream>>>(Wk, Wkb, DMOD * DMOD / 4);
  cast_f32_bf16<<<dim3(1024), dim3(256), 0, stream>>>(Wv, Wvb, DMOD * DMOD / 4);
  cast_f32_bf16<<<dim3(1024), dim3(256), 0, stream>>>(Wo, Wob, DMOD * DMOD / 4);

  dim3 blk(256);
  dim3 gProj(DMOD / 128, NTOK / 128);   // (8, 64)
  dim3 gS(NTOK / 128, NTOK / 128);      // (64, 64)

  // Q = (x Wq^T + bq) / sqrt(128)   [N,D] bf16
  gemm_bt<true, false, false, false><<<gProj, blk, 0, stream>>>(xb, Wqb, Qb, nullptr, bq, nullptr, NTOK, DMOD, DMOD, INV_SCALE);
  // K = x Wk^T + bk
  gemm_bt<true, false, false, false><<<gProj, blk, 0, stream>>>(xb, Wkb, Kb, nullptr, bk, nullptr, NTOK, DMOD, DMOD, 1.0f);
  // V^T = (x Wv^T + bv)^T  [D,N] bf16
  gemm_bt<true, true, false, false><<<gProj, blk, 0, stream>>>(xb, Wvb, Vt, nullptr, bv, nullptr, NTOK, DMOD, DMOD, 1.0f);
  // S = Q K^T  (scale folded into Q)  [N,N] bf16
  gemm_bt<false, false, false, false><<<gS, blk, 0, stream>>>(Qb, Kb, S, nullptr, nullptr, nullptr, NTOK, NTOK, DMOD, 1.0f);
  // softmax rows in-place
  softmax_inplace<<<dim3(NTOK), blk, 0, stream>>>(S);
  // O = att V  (= att (Vt)^T)  [N,D] bf16
  gemm_bt<false, false, false, false><<<gProj, blk, 0, stream>>>(S, Vt, Ob, nullptr, nullptr, nullptr, NTOK, DMOD, NTOK, 1.0f);
  // out = O Wo^T + bo + x  fp32
  gemm_bt<true, false, true, true><<<gProj, blk, 0, stream>>>(Ob, Wob, nullptr, out, bo, x, NTOK, DMOD, DMOD, 1.0f);
}

// Round 6
// 551.711 us; speedup vs baseline: 1.2702x; 1.2702x over previous
//
#include <hip/hip_runtime.h>
#include <stdint.h>

// Attention block: out = (softmax((x Wq^T + bq)(x Wk^T + bk)^T / sqrt(128)) (x Wv^T + bv)) Wo^T + bo + x
// N=8192 tokens, D=1024. bf16 MFMA GEMMs with 4-deep LDS pipeline, counted vmcnt,
// XOR-swizzled LDS (linear dest + pre-swizzled source + swizzled read), XCD swizzle.

#define NTOK 8192
#define DMOD 1024
static constexpr float INV_SCALE = 0.08838834764831845f; // 1/sqrt(128)

typedef __attribute__((ext_vector_type(8))) short short8;   // 8 bf16 MFMA fragment
typedef __attribute__((ext_vector_type(4))) float f32x4;
typedef __attribute__((ext_vector_type(8))) unsigned short u16x8;
typedef __attribute__((ext_vector_type(4))) unsigned short u16x4;

__device__ __forceinline__ unsigned short f2bf(float f) {
  union { float f; uint32_t u; } x{f};
  uint32_t r = x.u + 0x7fffu + ((x.u >> 16) & 1u);
  return (unsigned short)(r >> 16);
}
__device__ __forceinline__ float bf2f(unsigned short b) {
  return __uint_as_float(((uint32_t)b) << 16);
}
__device__ __forceinline__ void async16(void* lds, const void* g) {
  __builtin_amdgcn_global_load_lds((const __attribute__((address_space(1))) void*)g,
                                   (__attribute__((address_space(3))) void*)lds, 16, 0, 0);
}

// ---------------- cast f32 -> bf16 ----------------
__global__ __launch_bounds__(256) void cast_f32_bf16(const float* __restrict__ in,
                                                     unsigned short* __restrict__ out, int n4) {
  int i = blockIdx.x * 256 + threadIdx.x;
  int stride = gridDim.x * 256;
  for (; i < n4; i += stride) {
    float4 v = ((const float4*)in)[i];
    u16x4 o;
    o[0] = f2bf(v.x); o[1] = f2bf(v.y); o[2] = f2bf(v.z); o[3] = f2bf(v.w);
    ((u16x4*)out)[i] = o;
  }
}

// ---------------- pipelined GEMM: C = A (MxK) * B^T (B is NxK) ----------------
// BK=32. 4 LDS buffers; stage tile t+3 while computing tile t; vmcnt(12) counted wait
// (3 tiles x 4 loads in flight). LDS XOR swizzle: 16B slot c16 stored at c16^((row>>1)&3)
// -> pre-swizzle SOURCE column (global_load_lds dest must stay linear), swizzle READ.
// Wave grid WM x WN; per-wave output (M_REP*16) x (N_REP*16).
template<int BM, int BN, int WM, int WN, bool BIAS, bool TRANS, bool F32OUT, bool RES>
__global__ __launch_bounds__(WM*WN*64, 2) void gemm_pipe(
    const unsigned short* __restrict__ A, const unsigned short* __restrict__ B,
    unsigned short* __restrict__ O16, float* __restrict__ O32,
    const float* __restrict__ bias, const float* __restrict__ resid,
    int M, int N, int K, float scale)
{
  constexpr int THREADS = WM * WN * 64;
  constexpr int M_REP = BM / (WM * 16);
  constexpr int N_REP = BN / (WN * 16);
  constexpr int ABYTES = BM * 64;          // 32 bf16 cols = 64 B per row
  constexpr int BBYTES = BN * 64;
  constexpr int BUFB = ABYTES + BBYTES;
  constexpr int RPR = THREADS / 4;         // rows staged per round (4 slots of 16B per row)
  static_assert(BM == BN, "square tiles only");
  static_assert(BM * 64 == RPR * 64 * 2, "2 staging rounds per operand");

  __shared__ alignas(16) char lds[4 * BUFB];

  const int t = threadIdx.x;
  const int l = t & 63, w = t >> 6;
  const int wrow = (w / WN) * (M_REP * 16);
  const int wcol = (w % WN) * (N_REP * 16);

  // bijective XCD swizzle (m204)
  const int nwg = gridDim.x * gridDim.y;
  const int flat = blockIdx.y * gridDim.x + blockIdx.x;
  const int q8 = nwg >> 3, r8 = nwg & 7;
  const int xcd = flat & 7, pos = flat >> 3;
  const int swz = (xcd < r8 ? xcd * (q8 + 1) : r8 * (q8 + 1) + (xcd - r8) * q8) + pos;
  const int row0 = (swz / gridDim.x) * BM;
  const int col0 = (swz % gridDim.x) * BN;

  // staging constants: thread t covers (row = t>>2 [+RPR], 16B slot = t&3) of each operand.
  // source column is XOR-pre-swizzled so that a swizzled READ returns logical data (rule #21).
  const int sr0 = t >> 2, sr1 = (t >> 2) + RPR;
  const int c0 = ((t & 3) ^ ((sr0 >> 1) & 3)) * 8;
  const int c1 = ((t & 3) ^ ((sr1 >> 1) & 3)) * 8;
  const unsigned short* gsrc[4];
  int ldst[4];
  gsrc[0] = A + (size_t)(row0 + sr0) * K + c0;  ldst[0] = t * 16;
  gsrc[1] = A + (size_t)(row0 + sr1) * K + c1;  ldst[1] = t * 16 + RPR * 64;
  gsrc[2] = B + (size_t)(col0 + sr0) * K + c0;  ldst[2] = ABYTES + t * 16;
  gsrc[3] = B + (size_t)(col0 + sr1) * K + c1;  ldst[3] = ABYTES + t * 16 + RPR * 64;

  // fragment read offsets (loop-invariant): row r, logical slot l>>4 -> stored slot ^((r>>1)&3)
  int offA[M_REP], offB[N_REP];
#pragma unroll
  for (int m = 0; m < M_REP; ++m) {
    int r = wrow + m * 16 + (l & 15);
    offA[m] = r * 64 + (((l >> 4) ^ ((r >> 1) & 3)) * 16);
  }
#pragma unroll
  for (int n = 0; n < N_REP; ++n) {
    int r = wcol + n * 16 + (l & 15);
    offB[n] = ABYTES + r * 64 + (((l >> 4) ^ ((r >> 1) & 3)) * 16);
  }

  f32x4 acc[M_REP][N_REP] = {};
  const int KT = K / 32;

  // prologue: stage tiles 0,1,2 into bufs 0,1,2 (12 loads in flight)
#pragma unroll
  for (int j = 0; j < 3; ++j) {
    char* bb = lds + j * BUFB;
#pragma unroll
    for (int s = 0; s < 4; ++s) async16(bb + ldst[s], gsrc[s] + j * 32);
  }

  for (int t3 = 0; t3 < KT; ++t3) {
    // B1: all waves finished reading buf[(t3-1)&3] (its ds_reads completed per lgkmcnt)
    asm volatile("s_waitcnt lgkmcnt(0)" ::: "memory");
    __builtin_amdgcn_s_barrier();
    asm volatile("" ::: "memory");
    if (t3 + 3 < KT) {
      char* bb = lds + ((t3 + 3) & 3) * BUFB;
#pragma unroll
      for (int s = 0; s < 4; ++s) async16(bb + ldst[s], gsrc[s] + (size_t)(t3 + 3) * 32);
      asm volatile("s_waitcnt vmcnt(12)" ::: "memory");   // tile t3 landed; t3+1..t3+3 in flight
    } else if (t3 + 3 == KT) {
      asm volatile("s_waitcnt vmcnt(8)" ::: "memory");
    } else if (t3 + 2 == KT) {
      asm volatile("s_waitcnt vmcnt(4)" ::: "memory");
    } else {
      asm volatile("s_waitcnt vmcnt(0)" ::: "memory");
    }
    __builtin_amdgcn_s_barrier();   // B2: tile t3 visible to all waves
    asm volatile("" ::: "memory");

    const char* bb = lds + (t3 & 3) * BUFB;
    short8 af[M_REP], bf[N_REP];
#pragma unroll
    for (int m = 0; m < M_REP; ++m) af[m] = *(const short8*)(bb + offA[m]);
#pragma unroll
    for (int n = 0; n < N_REP; ++n) bf[n] = *(const short8*)(bb + offB[n]);
#pragma unroll
    for (int m = 0; m < M_REP; ++m)
#pragma unroll
      for (int n = 0; n < N_REP; ++n)
        acc[m][n] = __builtin_amdgcn_mfma_f32_16x16x32_bf16(af[m], bf[n], acc[m][n], 0, 0, 0);
  }

  // epilogue. C/D layout: col = lane&15, row = (lane>>4)*4 + j
  const int rr = (l >> 4) * 4;
#pragma unroll
  for (int m = 0; m < M_REP; ++m) {
#pragma unroll
    for (int n = 0; n < N_REP; ++n) {
#pragma unroll
      for (int j = 0; j < 4; ++j) {
        int r = row0 + wrow + m * 16 + rr + j;
        int c = col0 + wcol + n * 16 + (l & 15);
        float v = acc[m][n][j];
        if (BIAS) v += bias[c];
        v *= scale;
        if (RES) v += resid[(size_t)r * N + c];
        if (F32OUT) O32[(size_t)r * N + c] = v;
        else if (TRANS) O16[(size_t)c * M + r] = f2bf(v);
        else O16[(size_t)r * N + c] = f2bf(v);
      }
    }
  }
}

// ---------------- row softmax in-place on bf16 [8192 x 8192] ----------------
__global__ __launch_bounds__(256) void softmax_inplace(unsigned short* __restrict__ S) {
  __shared__ float red[8];
  const int t = threadIdx.x;
  unsigned short* rp = S + (size_t)blockIdx.x * NTOK;
  float v[32];
#pragma unroll
  for (int i = 0; i < 4; ++i) {
    u16x8 u = ((const u16x8*)rp)[t + i * 256];
#pragma unroll
    for (int j = 0; j < 8; ++j) v[i * 8 + j] = bf2f(u[j]);
  }
  float m = -1e30f;
#pragma unroll
  for (int k = 0; k < 32; ++k) m = fmaxf(m, v[k]);
#pragma unroll
  for (int o = 32; o; o >>= 1) m = fmaxf(m, __shfl_xor(m, o));
  if ((t & 63) == 0) red[t >> 6] = m;
  __syncthreads();
  m = fmaxf(fmaxf(red[0], red[1]), fmaxf(red[2], red[3]));
  float s = 0.f;
#pragma unroll
  for (int k = 0; k < 32; ++k) { v[k] = __expf(v[k] - m); s += v[k]; }
#pragma unroll
  for (int o = 32; o; o >>= 1) s += __shfl_xor(s, o);
  if ((t & 63) == 0) red[4 + (t >> 6)] = s;
  __syncthreads();
  s = red[4] + red[5] + red[6] + red[7];
  float inv = 1.0f / s;
#pragma unroll
  for (int i = 0; i < 4; ++i) {
    u16x8 u;
#pragma unroll
    for (int j = 0; j < 8; ++j) u[j] = f2bf(v[i * 8 + j] * inv);
    ((u16x8*)rp)[t + i * 256] = u;
  }
}

extern "C" void kernel_launch(void* const* d_in, const int* in_sizes, int n_in,
                              void* d_out, int out_size, void* d_ws, size_t ws_size,
                              hipStream_t stream) {
  const float* x  = (const float*)d_in[0];
  const float* Wq = (const float*)d_in[1];
  const float* bq = (const float*)d_in[2];
  const float* Wk = (const float*)d_in[3];
  const float* bk = (const float*)d_in[4];
  const float* Wv = (const float*)d_in[5];
  const float* bv = (const float*)d_in[6];
  const float* Wo = (const float*)d_in[7];
  const float* bo = (const float*)d_in[8];
  float* out = (float*)d_out;

  char* p = (char*)d_ws;
  unsigned short* xb  = (unsigned short*)p; p += (size_t)NTOK * DMOD * 2;   // 16 MB
  unsigned short* Wqb = (unsigned short*)p; p += (size_t)DMOD * DMOD * 2;   // 2 MB
  unsigned short* Wkb = (unsigned short*)p; p += (size_t)DMOD * DMOD * 2;
  unsigned short* Wvb = (unsigned short*)p; p += (size_t)DMOD * DMOD * 2;
  unsigned short* Wob = (unsigned short*)p; p += (size_t)DMOD * DMOD * 2;
  unsigned short* Qb  = (unsigned short*)p; p += (size_t)NTOK * DMOD * 2;
  unsigned short* Kb  = (unsigned short*)p; p += (size_t)NTOK * DMOD * 2;
  unsigned short* Vt  = (unsigned short*)p; p += (size_t)DMOD * NTOK * 2;   // V transposed [D][N]
  unsigned short* Ob  = (unsigned short*)p; p += (size_t)NTOK * DMOD * 2;
  unsigned short* S   = (unsigned short*)p; p += (size_t)NTOK * NTOK * 2;   // 128 MB

  cast_f32_bf16<<<dim3(2048), dim3(256), 0, stream>>>(x, xb, NTOK * DMOD / 4);
  cast_f32_bf16<<<dim3(1024), dim3(256), 0, stream>>>(Wq, Wqb, DMOD * DMOD / 4);
  cast_f32_bf16<<<dim3(1024), dim3(256), 0, stream>>>(Wk, Wkb, DMOD * DMOD / 4);
  cast_f32_bf16<<<dim3(1024), dim3(256), 0, stream>>>(Wv, Wvb, DMOD * DMOD / 4);
  cast_f32_bf16<<<dim3(1024), dim3(256), 0, stream>>>(Wo, Wob, DMOD * DMOD / 4);

  dim3 b512(512), b256(256);
  dim3 gS(NTOK / 256, NTOK / 256);      // (32, 32) for 256^2 tile
  dim3 gProj(DMOD / 128, NTOK / 128);   // (8, 64)  for 128^2 tile

  // Q = (x Wq^T + bq) / sqrt(128)
  gemm_pipe<128,128,2,2,true,false,false,false><<<gProj, b256, 0, stream>>>(xb, Wqb, Qb, nullptr, bq, nullptr, NTOK, DMOD, DMOD, INV_SCALE);
  // K = x Wk^T + bk
  gemm_pipe<128,128,2,2,true,false,false,false><<<gProj, b256, 0, stream>>>(xb, Wkb, Kb, nullptr, bk, nullptr, NTOK, DMOD, DMOD, 1.0f);
  // V^T = (x Wv^T + bv)^T   [D,N]
  gemm_pipe<128,128,2,2,true,true,false,false><<<gProj, b256, 0, stream>>>(xb, Wvb, Vt, nullptr, bv, nullptr, NTOK, DMOD, DMOD, 1.0f);
  // S = Q K^T (scale folded into Q)  [N,N], 256^2 tile
  gemm_pipe<256,256,2,4,false,false,false,false><<<gS, b512, 0, stream>>>(Qb, Kb, S, nullptr, nullptr, nullptr, NTOK, NTOK, DMOD, 1.0f);
  // softmax rows in-place
  softmax_inplace<<<dim3(NTOK), b256, 0, stream>>>(S);
  // O = att V = att (Vt)^T  [N,D]
  gemm_pipe<128,128,2,2,false,false,false,false><<<gProj, b256, 0, stream>>>(S, Vt, Ob, nullptr, nullptr, nullptr, NTOK, DMOD, NTOK, 1.0f);
  // out = O Wo^T + bo + x  fp32
  gemm_pipe<128,128,2,2,true,false,true,true><<<gProj, b256, 0, stream>>>(Ob, Wob, nullptr, out, bo, x, NTOK, DMOD, DMOD, 1.0f);
}